// Round 13
// baseline (47.195 us; speedup 1.0000x reference)
//
#include <hip/hip_runtime.h>

// SSIM v25: ZERO mid-kernel barriers. v24 (gload_lds + counted vmcnt,
// 43.5us) proved depth isn't the constraint; all pipes <35% busy while
// wall = 2.7x max(VALU 17us, mem 15us) -> the residual is the block-wide
// step convoy (17 s_barriers aligning 4 waves + 3 blocks in lockstep).
// v25 makes each wave autonomous: it gload_lds-loads its OWN 16-col
// window [tx0w-16, tx0w+32) (64B-aligned -> 16 lines/instr, v20-quality
// coalescing; 6 instr/chunk) into its OWN 6KB LDS buffer (double-
// buffered, 12KB/wave, 48KB/block). Same-wave gload_lds->ds_read orders
// by the wave's own counted vmcnt -> NO s_barrier until the final
// reduction. Intra-block window overlap dedups in L1/L2 (block footprint
// unchanged -> FETCH ~95MB). Source-side XOR seg-swizzle j^(r&3) keeps
// ds_read_b128 conflicts <=4-way. LDS slots reproduce v12's exact
// fragment floats -> bit-identical math (absmax exactly 0.0078125).
//
// Slot identity: instr g of img m, lane 4r+j -> LDS[wave][buf][m][g][r][j]
// holds global (row chunkrow+r, col tx0w-16+4*(4g+(j^(r&3)))). Fragment
// (row ln, cols tx0w-8+8lg..+7) = group g=(2+2lg)>>2, slots
// j=((2+2lg)&3)^(ln&3) and ((3+2lg)&3)^(ln&3) at row ln  [seg algebra:
// stored seg = 4g+(j^(r&3)), j=(s&3)^(ln&3), r=ln -> seg=s]. Checked.

typedef __attribute__((ext_vector_type(8))) short bf16x8;
typedef __attribute__((ext_vector_type(4))) float f32x4;

constexpr int TX   = 64;             // block out-cols (4 waves x 16)
constexpr int BY   = 256;            // block out-rows
constexpr int IMW  = 512;
constexpr int IMH  = 512;
constexpr int NPL  = 48;
constexpr int GX   = IMW / TX;       // 8
constexpr int GYB  = IMH / BY;       // 2
constexpr int NBLK = GX * GYB * NPL; // 768
constexpr int NCH  = BY / 16;        // 16; chunks 0..16
constexpr int WB   = 12288;          // per-wave LDS (2 bufs x 6KB)
constexpr float C1c = 0.01f * 0.01f;
constexpr float C2c = 0.03f * 0.03f;

union frag {
    bf16x8 f;
    unsigned int u[4];
    uint4 q;
};

// RNE f32->bf16 pair pack (setup kernel only).
__device__ __forceinline__ unsigned int pk_bf16(float lo, float hi) {
    unsigned int a = __float_as_uint(lo);
    unsigned int b = __float_as_uint(hi);
    a += 0x7FFFu + ((a >> 16) & 1u);
    b += 0x7FFFu + ((b >> 16) & 1u);
    return (b & 0xFFFF0000u) | (a >> 16);
}

// Fast pack: round-half-up + byte-perm merge (3 VALU ops per pair).
__device__ __forceinline__ unsigned int pk_rhu(float lo, float hi, unsigned sel) {
    unsigned int a = __float_as_uint(lo) + 0x8000u;
    unsigned int b = __float_as_uint(hi) + 0x8000u;
    unsigned int r;
    asm("v_perm_b32 %0, %1, %2, %3" : "=v"(r) : "v"(b), "v"(a), "s"(sel));
    return r;
}

// Normalized 11-tap Gaussian (sigma=1.5); wt[d] for d in [0,11), else 0.
__device__ __forceinline__ float wsel(int d) {
    float w = 0.f;
    w = (d == 0 || d == 10) ? 0.00102838f : w;
    w = (d == 1 || d == 9)  ? 0.00759876f : w;
    w = (d == 2 || d == 8)  ? 0.03600077f : w;
    w = (d == 3 || d == 7)  ? 0.10936082f : w;
    w = (d == 4 || d == 6)  ? 0.21300553f : w;
    w = (d == 5)            ? 0.26601171f : w;
    return w;
}

// Per-lane weight fragments (8 words/lane):
//   words 0..3: whf  — H-pass B-frag,  W[k][n] = wt[k-n-3],   k = lg*8+j
//   words 4..7: whv  — V-pass A-frag with permuted rows,
//                      W'[k][n] = wt[wr(k)-n-3],
//                      wr(k) = (j<4 ? lg*4+j : 12+lg*4+j), j = k&7
__global__ void ssim_weight_setup(unsigned int* __restrict__ wbuf)
{
    const int lane = threadIdx.x & 63;
    const int ln   = lane & 15;
    const int lg   = lane >> 4;
#pragma unroll
    for (int w = 0; w < 4; ++w) {
        const int ka = lg * 8 + 2 * w;
        wbuf[lane * 8 + w] = pk_bf16(wsel(ka - ln - 3), wsel(ka + 1 - ln - 3));
        const int j0  = 2 * w;
        const int wr0 = (j0 < 4) ? (lg * 4 + j0) : (12 + lg * 4 + j0);
        wbuf[lane * 8 + 4 + w] = pk_bf16(wsel(wr0 - ln - 3), wsel(wr0 + 1 - ln - 3));
    }
}

// H-pass for one chunk from this wave's LDS buffer: read 2 f4/img (the
// exact v12 fragment floats), zero-predicate, pack, 5 MFMAs -> packed D.
template<int OFF>
__device__ __forceinline__ void cstep(const char* ldsW, int ro0, int ro1, bool ok,
                                      const frag& whf, unsigned sel,
                                      uint2* __restrict__ D)
{
    float4 ra0 = *reinterpret_cast<const float4*>(ldsW + OFF + ro0);
    float4 ra1 = *reinterpret_cast<const float4*>(ldsW + OFF + ro1);
    float4 rb0 = *reinterpret_cast<const float4*>(ldsW + OFF + 3072 + ro0);
    float4 rb1 = *reinterpret_cast<const float4*>(ldsW + OFF + 3072 + ro1);
    const float4 zz = make_float4(0.f, 0.f, 0.f, 0.f);
    if (!ok) { ra0 = zz; ra1 = zz; rb0 = zz; rb1 = zz; }

    const f32x4 z = {0.f, 0.f, 0.f, 0.f};
    frag fa, fb, faa, fbb, fab;
    fa.u[0]  = pk_rhu(ra0.x, ra0.y, sel);          fb.u[0]  = pk_rhu(rb0.x, rb0.y, sel);
    faa.u[0] = pk_rhu(ra0.x*ra0.x, ra0.y*ra0.y, sel);
    fbb.u[0] = pk_rhu(rb0.x*rb0.x, rb0.y*rb0.y, sel);
    fab.u[0] = pk_rhu(ra0.x*rb0.x, ra0.y*rb0.y, sel);
    fa.u[1]  = pk_rhu(ra0.z, ra0.w, sel);          fb.u[1]  = pk_rhu(rb0.z, rb0.w, sel);
    faa.u[1] = pk_rhu(ra0.z*ra0.z, ra0.w*ra0.w, sel);
    fbb.u[1] = pk_rhu(rb0.z*rb0.z, rb0.w*rb0.w, sel);
    fab.u[1] = pk_rhu(ra0.z*rb0.z, ra0.w*rb0.w, sel);
    fa.u[2]  = pk_rhu(ra1.x, ra1.y, sel);          fb.u[2]  = pk_rhu(rb1.x, rb1.y, sel);
    faa.u[2] = pk_rhu(ra1.x*ra1.x, ra1.y*ra1.y, sel);
    fbb.u[2] = pk_rhu(rb1.x*rb1.x, rb1.y*rb1.y, sel);
    fab.u[2] = pk_rhu(ra1.x*rb1.x, ra1.y*rb1.y, sel);
    fa.u[3]  = pk_rhu(ra1.z, ra1.w, sel);          fb.u[3]  = pk_rhu(rb1.z, rb1.w, sel);
    faa.u[3] = pk_rhu(ra1.z*ra1.z, ra1.w*ra1.w, sel);
    fbb.u[3] = pk_rhu(rb1.z*rb1.z, rb1.w*rb1.w, sel);
    fab.u[3] = pk_rhu(ra1.z*rb1.z, ra1.w*rb1.w, sel);

    f32x4 d;
    d = __builtin_amdgcn_mfma_f32_16x16x32_bf16(fa.f,  whf.f, z, 0, 0, 0);
    D[0] = make_uint2(pk_rhu(d[0], d[1], sel), pk_rhu(d[2], d[3], sel));
    d = __builtin_amdgcn_mfma_f32_16x16x32_bf16(fb.f,  whf.f, z, 0, 0, 0);
    D[1] = make_uint2(pk_rhu(d[0], d[1], sel), pk_rhu(d[2], d[3], sel));
    d = __builtin_amdgcn_mfma_f32_16x16x32_bf16(faa.f, whf.f, z, 0, 0, 0);
    D[2] = make_uint2(pk_rhu(d[0], d[1], sel), pk_rhu(d[2], d[3], sel));
    d = __builtin_amdgcn_mfma_f32_16x16x32_bf16(fbb.f, whf.f, z, 0, 0, 0);
    D[3] = make_uint2(pk_rhu(d[0], d[1], sel), pk_rhu(d[2], d[3], sel));
    d = __builtin_amdgcn_mfma_f32_16x16x32_bf16(fab.f, whf.f, z, 0, 0, 0);
    D[4] = make_uint2(pk_rhu(d[0], d[1], sel), pk_rhu(d[2], d[3], sel));
}

// V-pass for one 16-row out-tile from D_prev (chunk t) + D_cur (chunk t+1).
__device__ __forceinline__ void vstep(const frag& whv,
                                      const uint2* __restrict__ Dp,
                                      const uint2* __restrict__ Dc,
                                      float& lsum)
{
    const f32x4 z = {0.f, 0.f, 0.f, 0.f};
    f32x4 res[5];
#pragma unroll
    for (int p = 0; p < 5; ++p) {
        frag Bf;
        Bf.u[0] = Dp[p].x; Bf.u[1] = Dp[p].y;
        Bf.u[2] = Dc[p].x; Bf.u[3] = Dc[p].y;
        res[p] = __builtin_amdgcn_mfma_f32_16x16x32_bf16(whv.f, Bf.f, z, 0, 0, 0);
    }
#pragma unroll
    for (int j = 0; j < 4; ++j) {
        const float mu1 = res[0][j];
        const float mu2 = res[1][j];
        const float m1s = mu1 * mu1;
        const float m2s = mu2 * mu2;
        const float m12 = mu1 * mu2;
        const float s11 = res[2][j] - m1s;
        const float s22 = res[3][j] - m2s;
        const float s12 = res[4][j] - m12;
        const float num = (2.f * m12 + C1c) * (2.f * s12 + C2c);
        const float den = (m1s + m2s + C1c) * (s11 + s22 + C2c);
        lsum = fmaf(num, __builtin_amdgcn_rcpf(den), lsum);
    }
}

__global__ __launch_bounds__(256, 3)
void ssim_mfma(const float* __restrict__ img1, const float* __restrict__ img2,
               const unsigned int* __restrict__ wbuf,
               float* __restrict__ partials)
{
    const int tid  = threadIdx.x;
    const int lane = tid & 63;
    const int wave = tid >> 6;        // 0..3
    const int ln   = lane & 15;
    const int lg   = lane >> 4;       // 0..3
    const int bx   = blockIdx.x;
    const int y0   = blockIdx.y * BY;
    const float* __restrict__ p1 = img1 + (size_t)blockIdx.z * (IMW * IMH);
    const float* __restrict__ p2 = img2 + (size_t)blockIdx.z * (IMW * IMH);
    const unsigned int sel = 0x07060302u;

    frag whf, whv;
    whf.q = reinterpret_cast<const uint4*>(wbuf)[lane * 2];
    whv.q = reinterpret_cast<const uint4*>(wbuf)[lane * 2 + 1];

    __shared__ __align__(16) char lds[4 * WB];     // 12 KB per wave
    __shared__ float wsum[4];
    const int wbase = wave * WB;
    const char* ldsW = lds + wbase;

    // ---- per-lane load constants: lane = 4r+j loads (row r, seg 4g+js)
    // of the wave window [tx0w-16, +48) floats; js = j ^ (r&3) (XOR bank
    // swizzle, within-line so coalescing is unaffected: 16 lines/instr).
    const int rr  = lane >> 2;
    const int jj  = lane & 3;
    const int js  = jj ^ (rr & 3);
    const int cA16 = bx * TX + wave * 16 - 16;     // 64B-aligned window base
    int cg0 = cA16 + 4 * (0 + js); cg0 = cg0 < 0 ? 0 : (cg0 > IMW - 4 ? IMW - 4 : cg0);
    int cg1 = cA16 + 4 * (4 + js); cg1 = cg1 < 0 ? 0 : (cg1 > IMW - 4 ? IMW - 4 : cg1);
    int cg2 = cA16 + 4 * (8 + js); cg2 = cg2 < 0 ? 0 : (cg2 > IMW - 4 ? IMW - 4 : cg2);

    // ---- fragment read offsets (loop-invariant): abs seg s0 = 2+2lg.
    const int s0 = 2 + 2 * lg;
    const int gg = s0 >> 2;
    const int ro0 = gg * 1024 + ln * 64 + (((s0 & 3) ^ (ln & 3)) << 4);
    const int ro1 = gg * 1024 + ln * 64 + ((((s0 + 1) & 3) ^ (ln & 3)) << 4);
    const int cbase = bx * TX + wave * 16 - 8 + lg * 8;
    const bool colok = ((unsigned)cbase <= (unsigned)(IMW - 8));

    uint2 DA[5], DB[5];
    float lsum = 0.f;

#define CLMP(r) ((r) < 0 ? 0 : ((r) > IMH - 1 ? IMH - 1 : (r)))
#define ISSUE(c, OFF) do{ \
    const int ir = CLMP(y0 + 16 * (c) - 8 + rr); \
    const float* r1 = p1 + (size_t)ir * IMW; \
    const float* r2 = p2 + (size_t)ir * IMW; \
    __builtin_amdgcn_global_load_lds( \
        (const __attribute__((address_space(1))) void*)(r1 + cg0), \
        (__attribute__((address_space(3))) void*)(lds + wbase + (OFF) + 0), 16, 0, 0); \
    __builtin_amdgcn_global_load_lds( \
        (const __attribute__((address_space(1))) void*)(r1 + cg1), \
        (__attribute__((address_space(3))) void*)(lds + wbase + (OFF) + 1024), 16, 0, 0); \
    __builtin_amdgcn_global_load_lds( \
        (const __attribute__((address_space(1))) void*)(r1 + cg2), \
        (__attribute__((address_space(3))) void*)(lds + wbase + (OFF) + 2048), 16, 0, 0); \
    __builtin_amdgcn_global_load_lds( \
        (const __attribute__((address_space(1))) void*)(r2 + cg0), \
        (__attribute__((address_space(3))) void*)(lds + wbase + (OFF) + 3072), 16, 0, 0); \
    __builtin_amdgcn_global_load_lds( \
        (const __attribute__((address_space(1))) void*)(r2 + cg1), \
        (__attribute__((address_space(3))) void*)(lds + wbase + (OFF) + 4096), 16, 0, 0); \
    __builtin_amdgcn_global_load_lds( \
        (const __attribute__((address_space(1))) void*)(r2 + cg2), \
        (__attribute__((address_space(3))) void*)(lds + wbase + (OFF) + 5120), 16, 0, 0); \
    } while (0)
#define VMW(n) do{ \
    asm volatile("s_waitcnt vmcnt(" #n ")" ::: "memory"); \
    __builtin_amdgcn_sched_barrier(0); } while (0)
#define ROWOK(c) (colok && ((unsigned)(y0 + 16 * (c) - 8 + ln) < (unsigned)IMH))

    // ---- prologue: chunk0 -> buf0, chunk1 -> buf1 (in flight); H(0).
    ISSUE(0, 0);
    ISSUE(1, 6144);
    VMW(6);                                // chunk0's 6 writes complete
    cstep<0>(ldsW, ro0, ro1, ROWOK(0), whf, sel, DA);

    // ---- main march, NO barriers: step c issues chunk c+1 into the buf
    // this wave finished reading at step c-1 (same-wave sequential -> no
    // race), waits its own vmcnt(6) (chunk c done, c+1 stays in flight),
    // computes chunk c, emits tile c-1.
    for (int u = 0; u < 7; ++u) {
        const int c = 2 * u + 1;           // odd: read buf1
        ISSUE(c + 1, 0);
        VMW(6);
        cstep<6144>(ldsW, ro0, ro1, ROWOK(c), whf, sel, DB);
        vstep(whv, DA, DB, lsum);
        ISSUE(c + 2, 6144);
        VMW(6);
        cstep<0>(ldsW, ro0, ro1, ROWOK(c + 1), whf, sel, DA);
        vstep(whv, DB, DA, lsum);
    }
    // c = 15
    ISSUE(16, 0);
    VMW(6);
    cstep<6144>(ldsW, ro0, ro1, ROWOK(15), whf, sel, DB);
    vstep(whv, DA, DB, lsum);
    // c = 16
    VMW(0);
    cstep<0>(ldsW, ro0, ro1, ROWOK(16), whf, sel, DA);
    vstep(whv, DB, DA, lsum);
#undef CLMP
#undef ISSUE
#undef VMW
#undef ROWOK

    // ---- Block reduction -> per-block partial (only barrier in kernel) ----
#pragma unroll
    for (int off = 32; off > 0; off >>= 1)
        lsum += __shfl_down(lsum, off, 64);

    if (lane == 0) wsum[wave] = lsum;
    __syncthreads();
    if (tid == 0) {
        float tot = wsum[0] + wsum[1] + wsum[2] + wsum[3];
        const int bid = (blockIdx.z * gridDim.y + blockIdx.y) * gridDim.x + blockIdx.x;
        partials[bid] = tot;
    }
}

__global__ __launch_bounds__(256)
void ssim_reduce_kernel(const float* __restrict__ partials,
                        float* __restrict__ out)
{
    __shared__ double sm[256];
    double s = 0.0;
    for (int i = threadIdx.x; i < NBLK; i += 256) s += (double)partials[i];
    sm[threadIdx.x] = s;
    __syncthreads();
    for (int stride = 128; stride > 0; stride >>= 1) {
        if (threadIdx.x < stride) sm[threadIdx.x] += sm[threadIdx.x + stride];
        __syncthreads();
    }
    if (threadIdx.x == 0) {
        double mean = sm[0] / (double)((size_t)NPL * IMW * IMH);
        out[0] = (float)(1.0 - mean);
    }
}

extern "C" void kernel_launch(void* const* d_in, const int* in_sizes, int n_in,
                              void* d_out, int out_size, void* d_ws, size_t ws_size,
                              hipStream_t stream)
{
    (void)in_sizes; (void)n_in; (void)out_size; (void)ws_size;
    const float* img1 = (const float*)d_in[0];
    const float* img2 = (const float*)d_in[1];
    float* out = (float*)d_out;

    unsigned int* wbuf = (unsigned int*)d_ws;              // 2 KB weight table
    float* partials = (float*)((char*)d_ws + 4096);        // NBLK floats

    ssim_weight_setup<<<1, 64, 0, stream>>>(wbuf);
    dim3 grid(GX, GYB, NPL);
    ssim_mfma<<<grid, 256, 0, stream>>>(img1, img2, wbuf, partials);
    ssim_reduce_kernel<<<1, 256, 0, stream>>>(partials, out);
}